// Round 4
// baseline (633.947 us; speedup 1.0000x reference)
//
#include <hip/hip_runtime.h>
#include <stdint.h>

// VectorQuantizer: z [32768,64], codebook [1024,64] (dtype sniffed bf16/f32).
// d_out FLOAT32: z_q_st [2097152] ++ loss [1] ++ indices [32768].
// Bit-exact replication of the reference f32 arithmetic (numpy pairwise sums,
// sequential non-fused dot, f32 final adds, first-index argmin).
//
// R7 == R6 resubmit (R6 bench died to "container failed twice" infra error;
// kernel audited: LDS 38.4KB, all loads in bounds, ws use 16.4KB).
// R6 vs R5 (273us vq, VALUBusy 29.6%): inner loop was latency-bound on global
// codebook loads (256KB thrashes L1, ~200cy L2, scalar dword loads). Now the
// codebook is staged through LDS in 8 chunks of 128 codes (converted to f32 on
// stage), inner loop reads broadcast ds_read_b128. Block = 32 rows x 8 parts,
// 1024 blocks. Cross-part merge is lexicographic (d2,k) == global first-index.
#define N_ROWS 32768
#define DIM 64
#define K_CODES 1024
#define ROWS_PER_BLOCK 32
#define PARTS 8
#define CHUNK 128
#define NCHUNK (K_CODES / CHUNK)              // 8
#define CODES_PER_PART (CHUNK / PARTS)        // 16 per chunk per thread
#define NBLOCKS (N_ROWS / ROWS_PER_BLOCK)     // 1024
#define N_ELEMS (N_ROWS * DIM)                // 2097152

// workspace layout (bytes):
// [0,4096)      float cc[1024]
// [4096,4100)   int flags  (bit0: z is bf16, bit1: cb is bf16)
// [8192,8192+NBLOCKS*8)  double partials[NBLOCKS]

__device__ __forceinline__ float bfbits(uint32_t b) { return __uint_as_float(b << 16); }

// round f32 -> nearest bf16 value, returned AS f32 (RNE; finite inputs)
__device__ __forceinline__ float round_bf16(float f) {
  uint32_t u = __float_as_uint(f);
  uint32_t r = ((u + 0x7FFFu + ((u >> 16) & 1u)) >> 16) << 16;
  return __uint_as_float(r);
}

// numpy pairwise_sum for n=64 (8 accumulators, 8 rounds, numpy's combine tree).
template <typename F>
__device__ __forceinline__ float np_sum64(F get) {
  float r0 = get(0), r1 = get(1), r2 = get(2), r3 = get(3);
  float r4 = get(4), r5 = get(5), r6 = get(6), r7 = get(7);
  for (int i = 8; i < 64; i += 8) {
    r0 = __fadd_rn(r0, get(i + 0)); r1 = __fadd_rn(r1, get(i + 1));
    r2 = __fadd_rn(r2, get(i + 2)); r3 = __fadd_rn(r3, get(i + 3));
    r4 = __fadd_rn(r4, get(i + 4)); r5 = __fadd_rn(r5, get(i + 5));
    r6 = __fadd_rn(r6, get(i + 6)); r7 = __fadd_rn(r7, get(i + 7));
  }
  return __fadd_rn(__fadd_rn(__fadd_rn(r0, r1), __fadd_rn(r2, r3)),
                   __fadd_rn(__fadd_rn(r4, r5), __fadd_rn(r6, r7)));
}

// Precompute: dtype sniff (block 0 writes flags) + cc_k = np.sum(c*c) per code.
__global__ __launch_bounds__(256) void vq_prep_kernel(
    const void* __restrict__ z, const void* __restrict__ cb,
    float* __restrict__ cc_out, int* __restrict__ flags) {
  const int tid = threadIdx.x;
  __shared__ int s_cnt[2];
  if (tid < 2) s_cnt[tid] = 0;
  __syncthreads();
  if (tid < 128) {
    uint32_t wc = ((const uint32_t*)cb)[(size_t)tid * 255];
    float vc = fabsf(bfbits(wc & 0xFFFFu));
    if (vc == 0.0f || (vc > 5.9e-8f && vc < 32.0f)) atomicAdd(&s_cnt[1], 1);
    if (blockIdx.x == 0) {
      uint32_t wz = ((const uint32_t*)z)[(size_t)tid * 8191];
      float vz = fabsf(bfbits(wz & 0xFFFFu));
      if (vz == 0.0f || (vz > 5.9e-8f && vz < 32.0f)) atomicAdd(&s_cnt[0], 1);
    }
  }
  __syncthreads();
  const bool cb_bf16 = s_cnt[1] >= 96;
  if (blockIdx.x == 0 && tid == 0)
    flags[0] = (s_cnt[0] >= 96 ? 1 : 0) | (cb_bf16 ? 2 : 0);

  const int kk = blockIdx.x * 256 + tid;
  float v;
  if (cb_bf16) {
    const uint16_t* cp = (const uint16_t*)cb + (size_t)kk * DIM;
    v = np_sum64([&](int d) { float c = bfbits((uint32_t)cp[d]);
                              return __fmul_rn(c, c); });
  } else {
    const float* cp = (const float*)cb + (size_t)kk * DIM;
    v = np_sum64([&](int d) { return __fmul_rn(cp[d], cp[d]); });
  }
  cc_out[kk] = v;
}

// Thread = (row r = tid&31, part = tid>>5). Per chunk of 128 codes staged in
// LDS, each thread scans codes [chunk*128 + part*16, +16) with 4-way ILP.
__global__ __launch_bounds__(256) void vq_kernel(
    const void* __restrict__ z, const void* __restrict__ cb,
    const float* __restrict__ cc_in, const int* __restrict__ flags,
    float* __restrict__ out, double* __restrict__ partials) {
  const int tid = threadIdx.x;
  const int fl = flags[0];
  const bool z_bf16  = (fl & 1) != 0;
  const bool cb_bf16 = (fl & 2) != 0;

  __shared__ float s_cc[K_CODES];                 // 4 KB
  __shared__ float s_chunk[CHUNK * DIM];          // 32 KB, f32 always
  __shared__ float s_best[256];
  __shared__ int s_k[256];
  __shared__ int s_win[ROWS_PER_BLOCK];
  __shared__ double s_loss[ROWS_PER_BLOCK];

  #pragma unroll
  for (int kk = tid; kk < K_CODES; kk += 256) s_cc[kk] = cc_in[kk];

  const int r = tid & (ROWS_PER_BLOCK - 1);
  const int part = tid >> 5;
  const size_t row = (size_t)blockIdx.x * ROWS_PER_BLOCK + r;

  // Load z row as exact f32 values (vectorized).
  float zf[DIM];
  if (z_bf16) {
    const uint4* p = (const uint4*)((const uint16_t*)z + row * DIM);
    #pragma unroll
    for (int j = 0; j < 8; ++j) {
      uint4 u = p[j];
      zf[j * 8 + 0] = bfbits(u.x & 0xFFFFu); zf[j * 8 + 1] = bfbits(u.x >> 16);
      zf[j * 8 + 2] = bfbits(u.y & 0xFFFFu); zf[j * 8 + 3] = bfbits(u.y >> 16);
      zf[j * 8 + 4] = bfbits(u.z & 0xFFFFu); zf[j * 8 + 5] = bfbits(u.z >> 16);
      zf[j * 8 + 6] = bfbits(u.w & 0xFFFFu); zf[j * 8 + 7] = bfbits(u.w >> 16);
    }
  } else {
    const float4* p = (const float4*)((const float*)z + row * DIM);
    #pragma unroll
    for (int j = 0; j < 16; ++j) {
      float4 v = p[j];
      zf[j * 4 + 0] = v.x; zf[j * 4 + 1] = v.y;
      zf[j * 4 + 2] = v.z; zf[j * 4 + 3] = v.w;
    }
  }
  // zz = np.sum(z*z, axis=1) in f32, numpy pairwise order.
  const float zz = np_sum64([&](int d) { return __fmul_rn(zf[d], zf[d]); });

  float best = 3.4e38f;
  int bk = 0;
  float4* s_chunk4 = (float4*)s_chunk;

  for (int c = 0; c < NCHUNK; ++c) {
    __syncthreads();  // previous chunk's compute done (and s_cc stores visible)
    // ---- stage chunk c (128 codes) into LDS as f32 ----
    if (cb_bf16) {
      const uint4* src = (const uint4*)((const uint16_t*)cb + (size_t)c * CHUNK * DIM);
      #pragma unroll
      for (int j = 0; j < 4; ++j) {
        int idx = tid + 256 * j;          // 1024 x 8 bf16
        uint4 u = src[idx];
        float4 lo, hi;
        lo.x = bfbits(u.x & 0xFFFFu); lo.y = bfbits(u.x >> 16);
        lo.z = bfbits(u.y & 0xFFFFu); lo.w = bfbits(u.y >> 16);
        hi.x = bfbits(u.z & 0xFFFFu); hi.y = bfbits(u.z >> 16);
        hi.z = bfbits(u.w & 0xFFFFu); hi.w = bfbits(u.w >> 16);
        s_chunk4[idx * 2] = lo;
        s_chunk4[idx * 2 + 1] = hi;
      }
    } else {
      const float4* src = (const float4*)((const float*)cb + (size_t)c * CHUNK * DIM);
      #pragma unroll
      for (int j = 0; j < 8; ++j) {
        int idx = tid + 256 * j;          // 2048 float4
        s_chunk4[idx] = src[idx];
      }
    }
    __syncthreads();

    // ---- scan this thread's 16 codes, 4-way ILP, broadcast LDS reads ----
    const int kbase = c * CHUNK + part * CODES_PER_PART;
    const int lbase = part * CODES_PER_PART;
    for (int kg = 0; kg < CODES_PER_PART; kg += 4) {
      const float4* cp = (const float4*)(s_chunk + (lbase + kg) * DIM);
      float g0 = 0.0f, g1 = 0.0f, g2 = 0.0f, g3 = 0.0f;
      #pragma unroll
      for (int d4 = 0; d4 < 16; ++d4) {
        float4 a = cp[d4], b = cp[d4 + 16], c2 = cp[d4 + 32], d3 = cp[d4 + 48];
        // strictly ascending d within each chain (numpy sequential order)
        g0 = __fadd_rn(g0, __fmul_rn(zf[4 * d4 + 0], a.x));
        g0 = __fadd_rn(g0, __fmul_rn(zf[4 * d4 + 1], a.y));
        g0 = __fadd_rn(g0, __fmul_rn(zf[4 * d4 + 2], a.z));
        g0 = __fadd_rn(g0, __fmul_rn(zf[4 * d4 + 3], a.w));
        g1 = __fadd_rn(g1, __fmul_rn(zf[4 * d4 + 0], b.x));
        g1 = __fadd_rn(g1, __fmul_rn(zf[4 * d4 + 1], b.y));
        g1 = __fadd_rn(g1, __fmul_rn(zf[4 * d4 + 2], b.z));
        g1 = __fadd_rn(g1, __fmul_rn(zf[4 * d4 + 3], b.w));
        g2 = __fadd_rn(g2, __fmul_rn(zf[4 * d4 + 0], c2.x));
        g2 = __fadd_rn(g2, __fmul_rn(zf[4 * d4 + 1], c2.y));
        g2 = __fadd_rn(g2, __fmul_rn(zf[4 * d4 + 2], c2.z));
        g2 = __fadd_rn(g2, __fmul_rn(zf[4 * d4 + 3], c2.w));
        g3 = __fadd_rn(g3, __fmul_rn(zf[4 * d4 + 0], d3.x));
        g3 = __fadd_rn(g3, __fmul_rn(zf[4 * d4 + 1], d3.y));
        g3 = __fadd_rn(g3, __fmul_rn(zf[4 * d4 + 2], d3.z));
        g3 = __fadd_rn(g3, __fmul_rn(zf[4 * d4 + 3], d3.w));
      }
      const int k = kbase + kg;
      float e0 = __fsub_rn(__fadd_rn(zz, s_cc[k + 0]), __fmul_rn(2.0f, g0));
      float e1 = __fsub_rn(__fadd_rn(zz, s_cc[k + 1]), __fmul_rn(2.0f, g1));
      float e2 = __fsub_rn(__fadd_rn(zz, s_cc[k + 2]), __fmul_rn(2.0f, g2));
      float e3 = __fsub_rn(__fadd_rn(zz, s_cc[k + 3]), __fmul_rn(2.0f, g3));
      if (e0 < best) { best = e0; bk = k + 0; }
      if (e1 < best) { best = e1; bk = k + 1; }
      if (e2 < best) { best = e2; bk = k + 2; }
      if (e3 < best) { best = e3; bk = k + 3; }
    }
  }

  s_best[tid] = best;
  s_k[tid] = bk;
  __syncthreads();

  if (tid < ROWS_PER_BLOCK) {
    // Parts interleave k -> merge with lexicographic (d2, k): exactly the
    // global first-index (numpy) argmin.
    float b = 3.4e38f;
    int bbk = 0x7FFFFFFF;
    for (int p = 0; p < PARTS; ++p) {
      float v = s_best[p * ROWS_PER_BLOCK + tid];
      int vk = s_k[p * ROWS_PER_BLOCK + tid];
      if (v < b || (v == b && vk < bbk)) { b = v; bbk = vk; }
    }
    s_win[tid] = bbk;
    // Exact squared distance of the winner (fp64) — thread tid owns row tid's zf
    // (tid < 32 => r == tid, part == 0).
    double acc = 0.0;
    if (cb_bf16) {
      const uint16_t* cp = (const uint16_t*)cb + (size_t)bbk * DIM;
      for (int d = 0; d < DIM; ++d) {
        double df = (double)zf[d] - (double)bfbits((uint32_t)cp[d]);
        acc = fma(df, df, acc);
      }
    } else {
      const float* cp = (const float*)cb + (size_t)bbk * DIM;
      for (int d = 0; d < DIM; ++d) {
        double df = (double)zf[d] - (double)cp[d];
        acc = fma(df, df, acc);
      }
    }
    s_loss[tid] = acc;
    const size_t myrow = (size_t)blockIdx.x * ROWS_PER_BLOCK + tid;
    out[(size_t)N_ELEMS + 1 + myrow] = round_bf16((float)bbk);
  }
  __syncthreads();

  // z_q write: 32 rows x 64 dims = 2048 floats, 256 threads x 8, coalesced.
  const size_t base = (size_t)blockIdx.x * ROWS_PER_BLOCK * DIM;
  #pragma unroll
  for (int j = 0; j < 8; ++j) {
    int idx = tid + 256 * j;
    int rr = idx >> 6, dd = idx & 63;
    int w = s_win[rr];
    float v;
    if (cb_bf16) v = bfbits((uint32_t)((const uint16_t*)cb)[(size_t)w * DIM + dd]);
    else         v = round_bf16(((const float*)cb)[(size_t)w * DIM + dd]);
    out[base + idx] = v;
  }

  if (tid == 0) {
    double s = 0.0;
    for (int i = 0; i < ROWS_PER_BLOCK; ++i) s += s_loss[i];
    partials[blockIdx.x] = s;
  }
}

__global__ __launch_bounds__(256) void vq_loss_kernel(
    const double* __restrict__ partials, float* __restrict__ out) {
  __shared__ double sh[256];
  const int tid = threadIdx.x;
  double s = 0.0;
  for (int i = tid; i < NBLOCKS; i += 256) s += partials[i];
  sh[tid] = s;
  __syncthreads();
  if (tid == 0) {
    double t = 0.0;
    for (int i = 0; i < 256; ++i) t += sh[i];
    out[N_ELEMS] = round_bf16((float)(1.25 * t / (double)N_ELEMS));
  }
}

extern "C" void kernel_launch(void* const* d_in, const int* in_sizes, int n_in,
                              void* d_out, int out_size, void* d_ws, size_t ws_size,
                              hipStream_t stream) {
  const void* z  = d_in[0];
  const void* cb = d_in[1];
  float* out = (float*)d_out;
  uint8_t* ws = (uint8_t*)d_ws;
  float* cc = (float*)ws;
  int* flags = (int*)(ws + 4096);
  double* partials = (double*)(ws + 8192);

  vq_prep_kernel<<<K_CODES / 256, 256, 0, stream>>>(z, cb, cc, flags);
  vq_kernel<<<NBLOCKS, 256, 0, stream>>>(z, cb, cc, flags, out, partials);
  vq_loss_kernel<<<1, 256, 0, stream>>>(partials, out);
}

// Round 5
// 310.303 us; speedup vs baseline: 2.0430x; 2.0430x over previous
//
#include <hip/hip_runtime.h>
#include <stdint.h>

// VectorQuantizer: z [32768,64], codebook [1024,64] (dtype sniffed bf16/f32).
// d_out FLOAT32: z_q_st [2097152] ++ loss [1] ++ indices [32768].
// Bit-exact replication of the reference f32 arithmetic (numpy pairwise sums,
// sequential non-fused dot, f32 final adds, first-index argmin).
//
// R8 vs R7 (590us, LDS-pipe-bound) and R5 (273us, scalar-global latency-bound):
// codebook stays in GLOBAL memory (L1/L2-resident) but loads are vectorized
// (uint4 = 8 bf16 / float4 = 4 f32 per inst, 8x/4x fewer VMEM instrs, 32
// independent loads per 4-code group) and parts interleave finely (part p owns
// codes 32g+4p..+4) so a block streams the codebook as ONE sequential pass
// (8KB active window, L1-friendly) instead of 8 thrashing slice streams.
// Cross-part merge is lexicographic (d2,k) == global first-index argmin.
#define N_ROWS 32768
#define DIM 64
#define K_CODES 1024
#define ROWS_PER_BLOCK 32
#define PARTS 8
#define NGROUPS (K_CODES / (PARTS * 4))       // 32 groups of 4 codes per part
#define NBLOCKS (N_ROWS / ROWS_PER_BLOCK)     // 1024
#define N_ELEMS (N_ROWS * DIM)                // 2097152

// workspace layout (bytes):
// [0,4096)      float cc[1024]
// [4096,4100)   int flags  (bit0: z is bf16, bit1: cb is bf16)
// [8192,8192+NBLOCKS*8)  double partials[NBLOCKS]

__device__ __forceinline__ float bfbits(uint32_t b) { return __uint_as_float(b << 16); }
__device__ __forceinline__ float bf_lo(uint32_t u) { return __uint_as_float(u << 16); }
__device__ __forceinline__ float bf_hi(uint32_t u) { return __uint_as_float(u & 0xFFFF0000u); }

// round f32 -> nearest bf16 value, returned AS f32 (RNE; finite inputs)
__device__ __forceinline__ float round_bf16(float f) {
  uint32_t u = __float_as_uint(f);
  uint32_t r = ((u + 0x7FFFu + ((u >> 16) & 1u)) >> 16) << 16;
  return __uint_as_float(r);
}

// numpy pairwise_sum for n=64 (8 accumulators, 8 rounds, numpy's combine tree).
template <typename F>
__device__ __forceinline__ float np_sum64(F get) {
  float r0 = get(0), r1 = get(1), r2 = get(2), r3 = get(3);
  float r4 = get(4), r5 = get(5), r6 = get(6), r7 = get(7);
  for (int i = 8; i < 64; i += 8) {
    r0 = __fadd_rn(r0, get(i + 0)); r1 = __fadd_rn(r1, get(i + 1));
    r2 = __fadd_rn(r2, get(i + 2)); r3 = __fadd_rn(r3, get(i + 3));
    r4 = __fadd_rn(r4, get(i + 4)); r5 = __fadd_rn(r5, get(i + 5));
    r6 = __fadd_rn(r6, get(i + 6)); r7 = __fadd_rn(r7, get(i + 7));
  }
  return __fadd_rn(__fadd_rn(__fadd_rn(r0, r1), __fadd_rn(r2, r3)),
                   __fadd_rn(__fadd_rn(r4, r5), __fadd_rn(r6, r7)));
}

// Precompute: dtype sniff (block 0 writes flags) + cc_k = np.sum(c*c) per code.
__global__ __launch_bounds__(256) void vq_prep_kernel(
    const void* __restrict__ z, const void* __restrict__ cb,
    float* __restrict__ cc_out, int* __restrict__ flags) {
  const int tid = threadIdx.x;
  __shared__ int s_cnt[2];
  if (tid < 2) s_cnt[tid] = 0;
  __syncthreads();
  if (tid < 128) {
    uint32_t wc = ((const uint32_t*)cb)[(size_t)tid * 255];
    float vc = fabsf(bfbits(wc & 0xFFFFu));
    if (vc == 0.0f || (vc > 5.9e-8f && vc < 32.0f)) atomicAdd(&s_cnt[1], 1);
    if (blockIdx.x == 0) {
      uint32_t wz = ((const uint32_t*)z)[(size_t)tid * 8191];
      float vz = fabsf(bfbits(wz & 0xFFFFu));
      if (vz == 0.0f || (vz > 5.9e-8f && vz < 32.0f)) atomicAdd(&s_cnt[0], 1);
    }
  }
  __syncthreads();
  const bool cb_bf16 = s_cnt[1] >= 96;
  if (blockIdx.x == 0 && tid == 0)
    flags[0] = (s_cnt[0] >= 96 ? 1 : 0) | (cb_bf16 ? 2 : 0);

  const int kk = blockIdx.x * 256 + tid;
  float v;
  if (cb_bf16) {
    const uint16_t* cp = (const uint16_t*)cb + (size_t)kk * DIM;
    v = np_sum64([&](int d) { float c = bfbits((uint32_t)cp[d]);
                              return __fmul_rn(c, c); });
  } else {
    const float* cp = (const float*)cb + (size_t)kk * DIM;
    v = np_sum64([&](int d) { return __fmul_rn(cp[d], cp[d]); });
  }
  cc_out[kk] = v;
}

// Thread = (row r = tid&31, part = tid>>5); part p scans codes 32g+4p..+4 for
// g = 0..31 (ascending k within thread), 4-way ILP, vectorized global loads.
__global__ __launch_bounds__(256) void vq_kernel(
    const void* __restrict__ z, const void* __restrict__ cb,
    const float* __restrict__ cc_in, const int* __restrict__ flags,
    float* __restrict__ out, double* __restrict__ partials) {
  const int tid = threadIdx.x;
  const int fl = flags[0];
  const bool z_bf16  = (fl & 1) != 0;
  const bool cb_bf16 = (fl & 2) != 0;

  __shared__ float s_cc[K_CODES];                 // 4 KB
  __shared__ float s_best[256];
  __shared__ int s_k[256];
  __shared__ int s_win[ROWS_PER_BLOCK];
  __shared__ double s_loss[ROWS_PER_BLOCK];

  #pragma unroll
  for (int kk = tid; kk < K_CODES; kk += 256) s_cc[kk] = cc_in[kk];

  const int r = tid & (ROWS_PER_BLOCK - 1);
  const int part = tid >> 5;
  const size_t row = (size_t)blockIdx.x * ROWS_PER_BLOCK + r;

  // Load z row as exact f32 values (vectorized).
  float zf[DIM];
  if (z_bf16) {
    const uint4* p = (const uint4*)((const uint16_t*)z + row * DIM);
    #pragma unroll
    for (int j = 0; j < 8; ++j) {
      uint4 u = p[j];
      zf[j * 8 + 0] = bf_lo(u.x); zf[j * 8 + 1] = bf_hi(u.x);
      zf[j * 8 + 2] = bf_lo(u.y); zf[j * 8 + 3] = bf_hi(u.y);
      zf[j * 8 + 4] = bf_lo(u.z); zf[j * 8 + 5] = bf_hi(u.z);
      zf[j * 8 + 6] = bf_lo(u.w); zf[j * 8 + 7] = bf_hi(u.w);
    }
  } else {
    const float4* p = (const float4*)((const float*)z + row * DIM);
    #pragma unroll
    for (int j = 0; j < 16; ++j) {
      float4 v = p[j];
      zf[j * 4 + 0] = v.x; zf[j * 4 + 1] = v.y;
      zf[j * 4 + 2] = v.z; zf[j * 4 + 3] = v.w;
    }
  }
  // zz = np.sum(z*z, axis=1) in f32, numpy pairwise order.
  const float zz = np_sum64([&](int d) { return __fmul_rn(zf[d], zf[d]); });

  __syncthreads();  // s_cc ready

  // Scan: d2 = fl(fl(zz + cc_k) - fl(2*g)), g = sequential f32 dot ascending d
  // (einsum inner loop, non-fused). Per-thread k ascending, strict < (np ties).
  float best = 3.4e38f;
  int bk = 0;
  if (cb_bf16) {
    for (int gi = 0; gi < NGROUPS; ++gi) {
      const int k = gi * 32 + part * 4;
      const uint4* c0 = (const uint4*)((const uint16_t*)cb + (size_t)(k + 0) * DIM);
      const uint4* c1 = (const uint4*)((const uint16_t*)cb + (size_t)(k + 1) * DIM);
      const uint4* c2 = (const uint4*)((const uint16_t*)cb + (size_t)(k + 2) * DIM);
      const uint4* c3 = (const uint4*)((const uint16_t*)cb + (size_t)(k + 3) * DIM);
      float g0 = 0.0f, g1 = 0.0f, g2 = 0.0f, g3 = 0.0f;
      #pragma unroll
      for (int j = 0; j < 8; ++j) {
        uint4 u0 = c0[j], u1 = c1[j], u2 = c2[j], u3 = c3[j];
        const int d0 = j * 8;
        g0 = __fadd_rn(g0, __fmul_rn(zf[d0 + 0], bf_lo(u0.x)));
        g0 = __fadd_rn(g0, __fmul_rn(zf[d0 + 1], bf_hi(u0.x)));
        g0 = __fadd_rn(g0, __fmul_rn(zf[d0 + 2], bf_lo(u0.y)));
        g0 = __fadd_rn(g0, __fmul_rn(zf[d0 + 3], bf_hi(u0.y)));
        g0 = __fadd_rn(g0, __fmul_rn(zf[d0 + 4], bf_lo(u0.z)));
        g0 = __fadd_rn(g0, __fmul_rn(zf[d0 + 5], bf_hi(u0.z)));
        g0 = __fadd_rn(g0, __fmul_rn(zf[d0 + 6], bf_lo(u0.w)));
        g0 = __fadd_rn(g0, __fmul_rn(zf[d0 + 7], bf_hi(u0.w)));
        g1 = __fadd_rn(g1, __fmul_rn(zf[d0 + 0], bf_lo(u1.x)));
        g1 = __fadd_rn(g1, __fmul_rn(zf[d0 + 1], bf_hi(u1.x)));
        g1 = __fadd_rn(g1, __fmul_rn(zf[d0 + 2], bf_lo(u1.y)));
        g1 = __fadd_rn(g1, __fmul_rn(zf[d0 + 3], bf_hi(u1.y)));
        g1 = __fadd_rn(g1, __fmul_rn(zf[d0 + 4], bf_lo(u1.z)));
        g1 = __fadd_rn(g1, __fmul_rn(zf[d0 + 5], bf_hi(u1.z)));
        g1 = __fadd_rn(g1, __fmul_rn(zf[d0 + 6], bf_lo(u1.w)));
        g1 = __fadd_rn(g1, __fmul_rn(zf[d0 + 7], bf_hi(u1.w)));
        g2 = __fadd_rn(g2, __fmul_rn(zf[d0 + 0], bf_lo(u2.x)));
        g2 = __fadd_rn(g2, __fmul_rn(zf[d0 + 1], bf_hi(u2.x)));
        g2 = __fadd_rn(g2, __fmul_rn(zf[d0 + 2], bf_lo(u2.y)));
        g2 = __fadd_rn(g2, __fmul_rn(zf[d0 + 3], bf_hi(u2.y)));
        g2 = __fadd_rn(g2, __fmul_rn(zf[d0 + 4], bf_lo(u2.z)));
        g2 = __fadd_rn(g2, __fmul_rn(zf[d0 + 5], bf_hi(u2.z)));
        g2 = __fadd_rn(g2, __fmul_rn(zf[d0 + 6], bf_lo(u2.w)));
        g2 = __fadd_rn(g2, __fmul_rn(zf[d0 + 7], bf_hi(u2.w)));
        g3 = __fadd_rn(g3, __fmul_rn(zf[d0 + 0], bf_lo(u3.x)));
        g3 = __fadd_rn(g3, __fmul_rn(zf[d0 + 1], bf_hi(u3.x)));
        g3 = __fadd_rn(g3, __fmul_rn(zf[d0 + 2], bf_lo(u3.y)));
        g3 = __fadd_rn(g3, __fmul_rn(zf[d0 + 3], bf_hi(u3.y)));
        g3 = __fadd_rn(g3, __fmul_rn(zf[d0 + 4], bf_lo(u3.z)));
        g3 = __fadd_rn(g3, __fmul_rn(zf[d0 + 5], bf_hi(u3.z)));
        g3 = __fadd_rn(g3, __fmul_rn(zf[d0 + 6], bf_lo(u3.w)));
        g3 = __fadd_rn(g3, __fmul_rn(zf[d0 + 7], bf_hi(u3.w)));
      }
      float e0 = __fsub_rn(__fadd_rn(zz, s_cc[k + 0]), __fmul_rn(2.0f, g0));
      float e1 = __fsub_rn(__fadd_rn(zz, s_cc[k + 1]), __fmul_rn(2.0f, g1));
      float e2 = __fsub_rn(__fadd_rn(zz, s_cc[k + 2]), __fmul_rn(2.0f, g2));
      float e3 = __fsub_rn(__fadd_rn(zz, s_cc[k + 3]), __fmul_rn(2.0f, g3));
      if (e0 < best) { best = e0; bk = k + 0; }
      if (e1 < best) { best = e1; bk = k + 1; }
      if (e2 < best) { best = e2; bk = k + 2; }
      if (e3 < best) { best = e3; bk = k + 3; }
    }
  } else {
    for (int gi = 0; gi < NGROUPS; ++gi) {
      const int k = gi * 32 + part * 4;
      const float4* c0 = (const float4*)((const float*)cb + (size_t)(k + 0) * DIM);
      const float4* c1 = (const float4*)((const float*)cb + (size_t)(k + 1) * DIM);
      const float4* c2 = (const float4*)((const float*)cb + (size_t)(k + 2) * DIM);
      const float4* c3 = (const float4*)((const float*)cb + (size_t)(k + 3) * DIM);
      float g0 = 0.0f, g1 = 0.0f, g2 = 0.0f, g3 = 0.0f;
      #pragma unroll
      for (int j = 0; j < 16; ++j) {
        float4 a = c0[j], b = c1[j], cc2 = c2[j], dd = c3[j];
        const int d0 = j * 4;
        g0 = __fadd_rn(g0, __fmul_rn(zf[d0 + 0], a.x));
        g0 = __fadd_rn(g0, __fmul_rn(zf[d0 + 1], a.y));
        g0 = __fadd_rn(g0, __fmul_rn(zf[d0 + 2], a.z));
        g0 = __fadd_rn(g0, __fmul_rn(zf[d0 + 3], a.w));
        g1 = __fadd_rn(g1, __fmul_rn(zf[d0 + 0], b.x));
        g1 = __fadd_rn(g1, __fmul_rn(zf[d0 + 1], b.y));
        g1 = __fadd_rn(g1, __fmul_rn(zf[d0 + 2], b.z));
        g1 = __fadd_rn(g1, __fmul_rn(zf[d0 + 3], b.w));
        g2 = __fadd_rn(g2, __fmul_rn(zf[d0 + 0], cc2.x));
        g2 = __fadd_rn(g2, __fmul_rn(zf[d0 + 1], cc2.y));
        g2 = __fadd_rn(g2, __fmul_rn(zf[d0 + 2], cc2.z));
        g2 = __fadd_rn(g2, __fmul_rn(zf[d0 + 3], cc2.w));
        g3 = __fadd_rn(g3, __fmul_rn(zf[d0 + 0], dd.x));
        g3 = __fadd_rn(g3, __fmul_rn(zf[d0 + 1], dd.y));
        g3 = __fadd_rn(g3, __fmul_rn(zf[d0 + 2], dd.z));
        g3 = __fadd_rn(g3, __fmul_rn(zf[d0 + 3], dd.w));
      }
      float e0 = __fsub_rn(__fadd_rn(zz, s_cc[k + 0]), __fmul_rn(2.0f, g0));
      float e1 = __fsub_rn(__fadd_rn(zz, s_cc[k + 1]), __fmul_rn(2.0f, g1));
      float e2 = __fsub_rn(__fadd_rn(zz, s_cc[k + 2]), __fmul_rn(2.0f, g2));
      float e3 = __fsub_rn(__fadd_rn(zz, s_cc[k + 3]), __fmul_rn(2.0f, g3));
      if (e0 < best) { best = e0; bk = k + 0; }
      if (e1 < best) { best = e1; bk = k + 1; }
      if (e2 < best) { best = e2; bk = k + 2; }
      if (e3 < best) { best = e3; bk = k + 3; }
    }
  }

  s_best[tid] = best;
  s_k[tid] = bk;
  __syncthreads();

  if (tid < ROWS_PER_BLOCK) {
    // Parts interleave k -> merge with lexicographic (d2, k): exactly the
    // global first-index (numpy) argmin.
    float b = 3.4e38f;
    int bbk = 0x7FFFFFFF;
    for (int p = 0; p < PARTS; ++p) {
      float v = s_best[p * ROWS_PER_BLOCK + tid];
      int vk = s_k[p * ROWS_PER_BLOCK + tid];
      if (v < b || (v == b && vk < bbk)) { b = v; bbk = vk; }
    }
    s_win[tid] = bbk;
    // Exact squared distance of the winner (fp64) — thread tid owns row tid's zf
    // (tid < 32 => r == tid, part == 0).
    double acc = 0.0;
    if (cb_bf16) {
      const uint16_t* cp = (const uint16_t*)cb + (size_t)bbk * DIM;
      for (int d = 0; d < DIM; ++d) {
        double df = (double)zf[d] - (double)bfbits((uint32_t)cp[d]);
        acc = fma(df, df, acc);
      }
    } else {
      const float* cp = (const float*)cb + (size_t)bbk * DIM;
      for (int d = 0; d < DIM; ++d) {
        double df = (double)zf[d] - (double)cp[d];
        acc = fma(df, df, acc);
      }
    }
    s_loss[tid] = acc;
    const size_t myrow = (size_t)blockIdx.x * ROWS_PER_BLOCK + tid;
    out[(size_t)N_ELEMS + 1 + myrow] = round_bf16((float)bbk);
  }
  __syncthreads();

  // z_q write: 32 rows x 64 dims = 2048 floats, 256 threads x 8, coalesced.
  const size_t base = (size_t)blockIdx.x * ROWS_PER_BLOCK * DIM;
  #pragma unroll
  for (int j = 0; j < 8; ++j) {
    int idx = tid + 256 * j;
    int rr = idx >> 6, dd = idx & 63;
    int w = s_win[rr];
    float v;
    if (cb_bf16) v = bfbits((uint32_t)((const uint16_t*)cb)[(size_t)w * DIM + dd]);
    else         v = round_bf16(((const float*)cb)[(size_t)w * DIM + dd]);
    out[base + idx] = v;
  }

  if (tid == 0) {
    double s = 0.0;
    for (int i = 0; i < ROWS_PER_BLOCK; ++i) s += s_loss[i];
    partials[blockIdx.x] = s;
  }
}

__global__ __launch_bounds__(256) void vq_loss_kernel(
    const double* __restrict__ partials, float* __restrict__ out) {
  __shared__ double sh[256];
  const int tid = threadIdx.x;
  double s = 0.0;
  for (int i = tid; i < NBLOCKS; i += 256) s += partials[i];
  sh[tid] = s;
  __syncthreads();
  if (tid == 0) {
    double t = 0.0;
    for (int i = 0; i < 256; ++i) t += sh[i];
    out[N_ELEMS] = round_bf16((float)(1.25 * t / (double)N_ELEMS));
  }
}

extern "C" void kernel_launch(void* const* d_in, const int* in_sizes, int n_in,
                              void* d_out, int out_size, void* d_ws, size_t ws_size,
                              hipStream_t stream) {
  const void* z  = d_in[0];
  const void* cb = d_in[1];
  float* out = (float*)d_out;
  uint8_t* ws = (uint8_t*)d_ws;
  float* cc = (float*)ws;
  int* flags = (int*)(ws + 4096);
  double* partials = (double*)(ws + 8192);

  vq_prep_kernel<<<K_CODES / 256, 256, 0, stream>>>(z, cb, cc, flags);
  vq_kernel<<<NBLOCKS, 256, 0, stream>>>(z, cb, cc, flags, out, partials);
  vq_loss_kernel<<<1, 256, 0, stream>>>(partials, out);
}